// Round 4
// baseline (320.398 us; speedup 1.0000x reference)
//
#include <hip/hip_runtime.h>
#include <hip/hip_bf16.h>

typedef short short8 __attribute__((ext_vector_type(8)));
typedef float f32x4 __attribute__((ext_vector_type(4)));

// ---------- helpers ----------
static __device__ __forceinline__ float bf2f(unsigned int b) { return __uint_as_float(b << 16); }
static __device__ __forceinline__ short fb2s(float x) {       // f32 -> bf16 (RNE, for prepack)
    unsigned u = __float_as_uint(x);
    return (short)((u + 0x7FFFu + ((u >> 16) & 1u)) >> 16);
}
// pack two f32 -> bf16x2 in one instruction (RNE)
static __device__ __forceinline__ unsigned int pack2(float lo, float hi) {
    unsigned int r;
    asm("v_cvt_pk_bf16_f32 %0, %1, %2" : "=v"(r) : "v"(lo), "v"(hi));
    return r;
}
// scaled silu: input y = 1.4427*x, returns 1.4427*silu(x) = y*rcp(1+2^-y)
// (the 1.4427 factors are folded into the prepacked weights)
static __device__ __forceinline__ float hsilu(float y) {
    return y * __builtin_amdgcn_rcpf(1.0f + __builtin_amdgcn_exp2f(-y));
}
static __device__ __forceinline__ float load1(const void* p, long off, int isbf) {
    return isbf ? bf2f(((const unsigned short*)p)[off]) : ((const float*)p)[off];
}
static __device__ __forceinline__ void load4(const void* p, long off, int isbf, float* o) {
    if (isbf) {
        uint2 v = *(const uint2*)((const unsigned short*)p + off);
        o[0]=bf2f(v.x&0xffffu); o[1]=bf2f(v.x>>16);
        o[2]=bf2f(v.y&0xffffu); o[3]=bf2f(v.y>>16);
    } else {
        float4 v = *(const float4*)((const float*)p + off);
        o[0]=v.x; o[1]=v.y; o[2]=v.z; o[3]=v.w;
    }
}
// per-wave dtype detection (deterministic, wave-uniform; no barrier needed)
static __device__ __forceinline__ int detect_bf16(const void* nf) {
    const unsigned int* w = (const unsigned int*)nf;
    int lane = threadIdx.x & 63;
    unsigned int e = (w[lane] >> 7) & 0xFFu;
    unsigned long long m = __ballot(e >= 118u && e <= 132u);
    return __popcll(m) >= 32 ? 1 : 0;
}

// ---------- fused kernel: prepack (blocks 0..43) + acc zero + per-node projections ----------
#define NB 32
__global__ __launch_bounds__(256) void k_node(
    const void* __restrict__ nf, const void* __restrict__ W0, const void* __restrict__ W1,
    const void* __restrict__ w1, const void* __restrict__ w2,
    const void* __restrict__ w3, const void* __restrict__ w4,
    short* __restrict__ Bws, float* __restrict__ NA, float* __restrict__ acc, int n_nodes) {
    __shared__ float Nd0[NB * 68];
    __shared__ float Nd1[3 * NB * 68];
    __shared__ float W0L[8 * 68];
    __shared__ float W1L[8 * 68];
    const int tid = threadIdx.x;
    const int isbf = detect_bf16(nf);
    const long n0 = (long)blockIdx.x * NB;

    // --- prepack MLP weights into MFMA fragment layout (first 44 blocks) ---
    // Fragment element (lane, j) = W[k = (lane>>4)*8+j][n = (lane&15)+tile*16];
    // this is simultaneously the B-frag of W and the A-frag of W^T (operand-swap safe).
    // exp2-fold: W1 carries an extra log2(e); layers 2/3 unchanged (factors cancel);
    // W4 carries 1/log2(e) = ln2 to remove it.
    if (blockIdx.x < 44) {
        int idx = blockIdx.x * 256 + tid;
        int j = idx & 7, lane = (idx >> 3) & 63, tile = idx >> 9;
        int n16 = lane & 15, kq = lane >> 4;
        float v;
        if (tile < 4) {
            int k = kq * 8 + j, n = tile * 16 + n16;
            v = (k < 8) ? load1(w1, k * 64 + n, isbf) * (0.35355339059327373f * 1.4426950408889634f) : 0.0f;
        } else if (tile < 12) {
            int t = (tile - 4) >> 1, kt = (tile - 4) & 1;
            int k = kt * 32 + kq * 8 + j, n = t * 16 + n16;
            v = load1(w2, k * 64 + n, isbf) * 0.125f;
        } else if (tile < 20) {
            int t = (tile - 12) >> 1, kt = (tile - 12) & 1;
            int k = kt * 32 + kq * 8 + j, n = t * 16 + n16;
            v = load1(w3, k * 64 + n, isbf) * 0.125f;
        } else {
            int kt = tile - 20;
            int k = kt * 32 + kq * 8 + j, n = n16;
            v = load1(w4, k * 16 + n, isbf) * (0.125f * 0.6931471805599453f);
        }
        Bws[idx] = fb2s(v);
    }
    // --- zero the edge accumulator ---
    if (tid < NB) {
        long n = n0 + tid;
        if (n < n_nodes) acc[n] = 0.0f;
    }
    if (n0 >= n_nodes) return;   // pure-prepack block (grid = max(nblk,44))

    // --- stage node_feats ---
    for (int i = tid; i < 512; i += 256) {
        W0L[(i >> 6) * 68 + (i & 63)] = load1(W0, i, isbf);
        W1L[(i >> 6) * 68 + (i & 63)] = load1(W1, i, isbf);
    }
    if (isbf) {
        for (int i = tid; i < NB * 32; i += 256) {
            int node = i >> 5, c8 = (i & 31) * 8;
            long ng = n0 + node; if (ng > n_nodes - 1) ng = n_nodes - 1;
            uint4 v = *(const uint4*)((const unsigned short*)nf + ng * 256 + c8);
            float f[8];
            f[0]=bf2f(v.x&0xffffu); f[1]=bf2f(v.x>>16);
            f[2]=bf2f(v.y&0xffffu); f[3]=bf2f(v.y>>16);
            f[4]=bf2f(v.z&0xffffu); f[5]=bf2f(v.z>>16);
            f[6]=bf2f(v.w&0xffffu); f[7]=bf2f(v.w>>16);
            #pragma unroll
            for (int t = 0; t < 8; t++) {
                int col = c8 + t;
                if (col < 64) Nd0[node * 68 + col] = f[t];
                else {
                    int cc = col - 64, vv = cc / 3, kk = cc - vv * 3;
                    Nd1[(kk * NB + node) * 68 + vv] = f[t];
                }
            }
        }
    } else {
        for (int i = tid; i < NB * 64; i += 256) {
            int node = i >> 6, c4 = (i & 63) * 4;
            long ng = n0 + node; if (ng > n_nodes - 1) ng = n_nodes - 1;
            float4 v = *(const float4*)((const float*)nf + ng * 256 + c4);
            float f[4] = {v.x, v.y, v.z, v.w};
            #pragma unroll
            for (int t = 0; t < 4; t++) {
                int col = c4 + t;
                if (col < 64) Nd0[node * 68 + col] = f[t];
                else {
                    int cc = col - 64, vv = cc / 3, kk = cc - vv * 3;
                    Nd1[(kk * NB + node) * 68 + vv] = f[t];
                }
            }
        }
    }
    __syncthreads();

    const int wv = tid >> 6, lane = tid & 63;
    const int u = lane & 7, ln = lane >> 3;
    float sum[4] = {0.0f, 0.0f, 0.0f, 0.0f};

    if (wv == 0) {
        const float* w = &W0L[u * 68];
        for (int v0 = 0; v0 < 64; v0 += 4) {
            float4 w4 = *(const float4*)(w + v0);
            #pragma unroll
            for (int j = 0; j < 4; j++) {
                float4 nd = *(const float4*)&Nd0[(ln + 8 * j) * 68 + v0];
                sum[j] += w4.x * nd.x + w4.y * nd.y + w4.z * nd.z + w4.w * nd.w;
            }
        }
        #pragma unroll
        for (int j = 0; j < 4; j++) {
            long node = n0 + ln + 8 * j;
            if (node < n_nodes) NA[node * 32 + u] = sum[j] * 0.03125f;
        }
    } else {
        const int kk = wv - 1;
        const float* w = &W1L[u * 68];
        const float* nd1 = &Nd1[kk * NB * 68];
        for (int v0 = 0; v0 < 64; v0 += 4) {
            float4 w4 = *(const float4*)(w + v0);
            #pragma unroll
            for (int j = 0; j < 4; j++) {
                float4 nd = *(const float4*)&nd1[(ln + 8 * j) * 68 + v0];
                sum[j] += w4.x * nd.x + w4.y * nd.y + w4.z * nd.z + w4.w * nd.w;
            }
        }
        #pragma unroll
        for (int j = 0; j < 4; j++) {
            long node = n0 + ln + 8 * j;
            if (node < n_nodes) NA[node * 32 + 8 + u * 3 + kk] = sum[j] * 0.018042195912175804f;
        }
    }
}

// ---------- MFMA edge kernel (operand-swapped: D = W^T @ H^T), 16-edge tiles ----------
// H layout (per wave, 16 rows x 72 shorts): physical short idx =
//   row*72 + ((col>>3) ^ ((row>>3)&1))*8 + (col&7);  row = edge-in-tile, col = feature.
// Read  (B-frag of H^T): lane(n16,kq) reads row=n16, cols kt*32+kq*8..+7 -> one b128.
// Write (D of Y^T):      lane(n16,kq) writes row=n16, cols t*16+kq*4..+3 -> one b64.
// Epilogue fully in-register: lane(n16,kq) holds feats kq*4..+3 of edge n16 after
// layer 4; partial dot per lane, then shfl_xor(16)+shfl_xor(32) reduce over kq.
// LDS = 22528 (W) + 4*2304 (H) = 31744 B -> 5 blocks/CU.
__global__ __launch_bounds__(256, 5) void k_edges_mfma(
    const void* __restrict__ ef, const void* __restrict__ ea, const void* __restrict__ qc,
    const int* __restrict__ eidx, const void* __restrict__ nf,
    const short* __restrict__ Bws, const float* __restrict__ NA,
    float* __restrict__ acc, int n_edges) {
    __shared__ __align__(16) short W[11264];
    __shared__ __align__(16) short Hs[4 * 1152];
    const int tid = threadIdx.x, lane = tid & 63, wv = tid >> 6;
    const int n16 = lane & 15, kq = lane >> 4;
    const int isbf = detect_bf16(nf);

    {
        const uint4* src = (const uint4*)Bws;
        uint4* dst = (uint4*)W;
        for (int i = tid; i < 1408; i += 256) dst[i] = src[i];
    }
    __syncthreads();

    short* Hw = Hs + wv * 1152;
    const int rbit = (n16 >> 3) & 1;                 // swizzle bit (shared by reads+writes)
    const int wrow = n16 * 72 + ((kq & 1) << 2);     // per-lane write base within a row
    const int kql = (kq & 1) << 2;                   // q-feature offset for epilogue
    const f32x4 zero = {0.0f, 0.0f, 0.0f, 0.0f};

    for (int half = 0; half < 2; half++) {
        #pragma unroll
        for (int nt = 0; nt < 2; nt++) {
            const long E0 = (long)blockIdx.x * 256 + half * 128 + wv * 32 + nt * 16;
            const long e = E0 + n16;                 // this lane's edge (4 lanes per edge)
            long ec = e; if (ec > n_edges - 1) ec = n_edges - 1;

            // ---- epilogue gathers, phase 1: edge-indexed ----
            const int s_nd = eidx[ec];
            const int r_nd = eidx[(long)n_edges + ec];
            float eav[4];
            load4(ea, ec * 4, isbf, eav);

            // ---- layer-1 B operand: edge_feats^T fragment ----
            short8 a1 = {0,0,0,0,0,0,0,0};
            if (kq == 0) {
                if (isbf) {
                    a1 = *(const short8*)((const unsigned short*)ef + ec * 8);
                } else {
                    const float* pe = (const float*)ef + ec * 8;
                    float4 v0 = *(const float4*)pe, v1 = *(const float4*)(pe + 4);
                    a1[0]=fb2s(v0.x); a1[1]=fb2s(v0.y); a1[2]=fb2s(v0.z); a1[3]=fb2s(v0.w);
                    a1[4]=fb2s(v1.x); a1[5]=fb2s(v1.y); a1[6]=fb2s(v1.z); a1[7]=fb2s(v1.w);
                }
            }

            {   // layer 1: Y^T[feat][edge] = W1^T @ X^T
                f32x4 c1[4];
                #pragma unroll
                for (int t = 0; t < 4; t++) {
                    short8 b = *(const short8*)(W + t * 512 + lane * 8);
                    c1[t] = __builtin_amdgcn_mfma_f32_16x16x32_bf16(b, a1, zero, 0, 0, 0);
                }
                #pragma unroll
                for (int t = 0; t < 4; t++) {
                    uint2 pkd;
                    pkd.x = pack2(hsilu(c1[t][0]), hsilu(c1[t][1]));
                    pkd.y = pack2(hsilu(c1[t][2]), hsilu(c1[t][3]));
                    *(uint2*)(Hw + wrow + (((t * 2 + (kq >> 1)) ^ rbit) << 3)) = pkd;
                }
            }

            // ---- epilogue gathers, phase 2: node-indexed, hide under layers 2-4 ----
            float q4[4];
            load4(qc, (long)s_nd * 8 + kql, isbf, q4);
            float na[12];
            const float* nr = NA + (long)r_nd * 32;
            if (kq < 2) {
                *(float4*)na = *(const float4*)(nr + (kq << 2));
            } else {
                *(float4*)(na + 0) = *(const float4*)(nr + 8 + (kq - 2) * 12);
                *(float4*)(na + 4) = *(const float4*)(nr + 12 + (kq - 2) * 12);
                *(float4*)(na + 8) = *(const float4*)(nr + 16 + (kq - 2) * 12);
            }

            #pragma unroll
            for (int L = 0; L < 2; L++) {   // layers 2,3: Y^T = W^T(64x64) @ H^T
                const int base = (L == 0) ? 4 : 12;
                short8 aH[2];
                #pragma unroll
                for (int kt = 0; kt < 2; kt++)
                    aH[kt] = *(const short8*)(Hw + n16 * 72 + (((kt * 4 + kq) ^ rbit) << 3));
                f32x4 c2[4];
                #pragma unroll
                for (int t = 0; t < 4; t++) c2[t] = zero;
                #pragma unroll
                for (int kt = 0; kt < 2; kt++)
                    #pragma unroll
                    for (int t = 0; t < 4; t++) {
                        short8 b = *(const short8*)(W + (base + t * 2 + kt) * 512 + lane * 8);
                        c2[t] = __builtin_amdgcn_mfma_f32_16x16x32_bf16(b, aH[kt], c2[t], 0, 0, 0);
                    }
                #pragma unroll
                for (int t = 0; t < 4; t++) {
                    uint2 pkd;
                    pkd.x = pack2(hsilu(c2[t][0]), hsilu(c2[t][1]));
                    pkd.y = pack2(hsilu(c2[t][2]), hsilu(c2[t][3]));
                    *(uint2*)(Hw + wrow + (((t * 2 + (kq >> 1)) ^ rbit) << 3)) = pkd;
                }
            }

            f32x4 c4 = zero;
            {   // layer 4: 16 outputs per edge
                short8 aH[2];
                #pragma unroll
                for (int kt = 0; kt < 2; kt++)
                    aH[kt] = *(const short8*)(Hw + n16 * 72 + (((kt * 4 + kq) ^ rbit) << 3));
                #pragma unroll
                for (int kt = 0; kt < 2; kt++) {
                    short8 b = *(const short8*)(W + (20 + kt) * 512 + lane * 8);
                    c4 = __builtin_amdgcn_mfma_f32_16x16x32_bf16(b, aH[kt], c4, 0, 0, 0);
                }
            }

            {   // epilogue in-register: lane holds feats kq*4..+3 of edge n16
                float p = 0.0f;
                if (kq < 2) {
                    #pragma unroll
                    for (int r = 0; r < 4; r++) p += c4[r] * q4[r] * na[r];
                    p *= eav[0];
                } else {
                    #pragma unroll
                    for (int r = 0; r < 4; r++) {
                        float d = eav[1] * na[r * 3] + eav[2] * na[r * 3 + 1] + eav[3] * na[r * 3 + 2];
                        p += c4[r] * q4[r] * d;
                    }
                }
                p += __shfl_xor(p, 16);
                p += __shfl_xor(p, 32);
                if (kq == 0 && e < n_edges) atomicAdd(&acc[r_nd], p);
            }
        }
    }
}

// ---------- accumulator -> output ----------
__global__ void k_out(const float* __restrict__ acc, void* __restrict__ out,
                      const void* __restrict__ nf, int n) {
    const int isbf = detect_bf16(nf);
    int i = blockIdx.x * 256 + threadIdx.x;
    if (i >= n) return;
    if (isbf) ((__hip_bfloat16*)out)[i] = __float2bfloat16(acc[i]);
    else      ((float*)out)[i] = acc[i];
}

// ---------- launch ----------
extern "C" void kernel_launch(void* const* d_in, const int* in_sizes, int n_in,
                              void* d_out, int out_size, void* d_ws, size_t ws_size,
                              hipStream_t stream) {
    const void* node_feats      = d_in[0];
    const void* charges_induced = d_in[2];
    const void* edge_feats      = d_in[3];
    const void* edge_attrs      = d_in[4];
    const void* mlp_w1          = d_in[6];
    const void* mlp_w2          = d_in[7];
    const void* mlp_w3          = d_in[8];
    const void* mlp_w4          = d_in[9];
    const void* W0              = d_in[10];
    const void* W1              = d_in[11];
    const int*  edge_index      = (const int*)d_in[12];

    const int n_nodes = in_sizes[0] / 256;
    const int n_edges = in_sizes[3] / 8;

    short* Bws = (short*)d_ws;                                 // 11264 shorts
    float* NA  = (float*)((char*)d_ws + 22528);                // n_nodes*32 f32
    float* acc = NA + (size_t)n_nodes * 32;                    // n_nodes f32

    int nblk = (n_nodes + NB - 1) / NB;
    if (nblk < 44) nblk = 44;
    k_node<<<nblk, 256, 0, stream>>>(node_feats, W0, W1,
        mlp_w1, mlp_w2, mlp_w3, mlp_w4, Bws, NA, acc, n_nodes);
    k_edges_mfma<<<(n_edges + 255) / 256, 256, 0, stream>>>(
        edge_feats, edge_attrs, charges_induced, edge_index, node_feats, Bws, NA, acc, n_edges);
    k_out<<<(n_nodes + 255) / 256, 256, 0, stream>>>(acc, d_out, node_feats, n_nodes);
}